// Round 6
// baseline (537.720 us; speedup 1.0000x reference)
//
#include <hip/hip_runtime.h>

// GAT self-attention: Wh = h@W; out = softmax(leaky_relu(Wh@Wh^T)) @ Wh
// N=8192, IN_F=256, OUT_F=128. adj input unused by the math.
//
// Round 5 (resubmit — prior bench died on container acquisition, kernel
// never measured): r3 flash structure EXACTLY (BM=64, 4 waves, 3 blocks/CU,
// NSPLIT=6 — r4 proved occupancy > DS amortization), but V fragments read
// straight from global WhT16 (L2-resident, 4MiB working set) instead of
// staging Vtsh: DS ops 42 -> 26 per wave per tile, LDS 45KB -> 26KB.
// V-loads issued split-half (8 pre-softmax, 8 pre-PV) so L2 latency hides
// under VALU/MFMA while holding only 32 extra VGPRs. Plus r4's
// coalesced-transpose wh_kernel (removes the 32x write-amplified scatter).

#define SEQ   8192
#define DIM   128
#define IN_F  256
#define BM    64
#define BN    64
#define NSPLIT 6
#define NKT   (SEQ / BN)      // 128 key tiles total

typedef __attribute__((ext_vector_type(8))) _Float16 f16x8;
typedef __attribute__((ext_vector_type(4))) _Float16 f16x4;
typedef __attribute__((ext_vector_type(4))) float   floatx4;

// ---------------------------------------------------------------------------
// Kernel 1: Wh = h @ W (fp32 accum) -> Wh16 row-major (coalesced) and WhT16
// via LDS transpose (coalesced f16x8 stores). 128 blocks x 64 rows.
// ---------------------------------------------------------------------------
__global__ __launch_bounds__(256) void wh_kernel(
    const float* __restrict__ h, const float* __restrict__ W,
    _Float16* __restrict__ Wh16, _Float16* __restrict__ WhT16) {
  __shared__ _Float16 T[64 * 132];            // pad 132 breaks pow-2 stride
  int tid = threadIdx.x;
  int cg  = tid & 31;                         // column group: 4 fp32 cols
  int rl  = tid >> 5;                         // 0..7
  int rowbase = blockIdx.x * 64;
  const float4* W4 = (const float4*)W;        // [256][32] of float4
#pragma unroll 2
  for (int sub = 0; sub < 8; sub++) {
    int row = rowbase + sub * 8 + rl;
    const float4* h4 = (const float4*)(h + (size_t)row * IN_F);
    float4 acc = make_float4(0.f, 0.f, 0.f, 0.f);
#pragma unroll 8
    for (int k4 = 0; k4 < IN_F / 4; k4++) {
      float4 hv = h4[k4];
      float4 w0 = W4[(k4 * 4 + 0) * 32 + cg];
      float4 w1 = W4[(k4 * 4 + 1) * 32 + cg];
      float4 w2 = W4[(k4 * 4 + 2) * 32 + cg];
      float4 w3 = W4[(k4 * 4 + 3) * 32 + cg];
      acc.x += hv.x * w0.x + hv.y * w1.x + hv.z * w2.x + hv.w * w3.x;
      acc.y += hv.x * w0.y + hv.y * w1.y + hv.z * w2.y + hv.w * w3.y;
      acc.z += hv.x * w0.z + hv.y * w1.z + hv.z * w2.z + hv.w * w3.z;
      acc.w += hv.x * w0.w + hv.y * w1.w + hv.z * w2.w + hv.w * w3.w;
    }
    f16x4 r;
    r[0] = (_Float16)acc.x; r[1] = (_Float16)acc.y;
    r[2] = (_Float16)acc.z; r[3] = (_Float16)acc.w;
    *(f16x4*)&Wh16[(size_t)row * DIM + cg * 4] = r;
    *(f16x4*)&T[(sub * 8 + rl) * 132 + cg * 4] = r;
  }
  __syncthreads();
  // WhT16[d][rowbase..+63]: 128 d x 8 row-chunks; 8 consecutive lanes write
  // 128B contiguous.
#pragma unroll
  for (int p = 0; p < 4; p++) {
    int chunk = p * 256 + tid;
    int d  = chunk >> 3;
    int rc = chunk & 7;
    f16x8 v;
#pragma unroll
    for (int i = 0; i < 8; i++) v[i] = T[(rc * 8 + i) * 132 + d];
    *(f16x8*)&WhT16[(size_t)d * SEQ + rowbase + rc * 8] = v;
  }
}

// ---------------------------------------------------------------------------
// Kernel 2: flash attention, swapped-QK^T form. grid = (128 qtiles, NSPLIT),
// block = 256 (4 waves); wave w owns Q rows [qtile*64 + w*16, +16).
// LDS: Ksh [64][136] + Psh [4][16][72] = 13312 halves = 26624 B.
// V fragments come from global WhT16 (same addresses Vtsh reads used in r3).
// ---------------------------------------------------------------------------
__global__ __launch_bounds__(256, 3) void flash_kernel(
    const _Float16* __restrict__ Wh16, const _Float16* __restrict__ WhT16,
    float* __restrict__ Opart, float* __restrict__ mpart,
    float* __restrict__ lpart) {
  __shared__ _Float16 lds[13312];
  _Float16* Ksh = lds;                      // 64*136  = 8704 halves
  _Float16* Psh = lds + 8704;               // 4*16*72 = 4608

  const int tid  = threadIdx.x;
  const int lane = tid & 63;
  const int wave = tid >> 6;
  const int n16  = lane & 15;
  const int quad = lane >> 4;

  const int qbase  = blockIdx.x * BM + wave * 16;
  const int sp     = blockIdx.y;
  const int tstart = (sp * NKT) / NSPLIT;
  const int tend   = ((sp + 1) * NKT) / NSPLIT;
  const int jbase0 = tstart * BN;
  const int jcount = tend - tstart;          // 21 or 22

  // Q fragments (B operand): qf[c] = Q[qbase+n16][c*32+quad*8+j]
  f16x8 qf[4];
#pragma unroll
  for (int c = 0; c < 4; c++)
    qf[c] = *(const f16x8*)&Wh16[(size_t)(qbase + n16) * DIM + c * 32 + quad * 8];

  // K staging (identical to r3's K half)
  const int krow = tid >> 4;
  const int kcol = (tid & 15) * 8;
  f16x8 kreg[4];
  auto stage_load = [&](int jb) {
#pragma unroll
    for (int rep = 0; rep < 4; rep++)
      kreg[rep] = *(const f16x8*)&Wh16[(size_t)(jb + rep * 16 + krow) * DIM + kcol];
  };
  auto stage_write = [&]() {
#pragma unroll
    for (int rep = 0; rep < 4; rep++)
      *(f16x8*)&Ksh[(rep * 16 + krow) * 136 + kcol] = kreg[rep];
  };

  // V fragment base (per-lane): vf[ct][c] = WhT16[(ct*16+n16)*SEQ + jbase + c*32 + quad*8]
  const _Float16* Vg = WhT16 + (size_t)n16 * SEQ + quad * 8;

  // O^T accumulators: o[ct][e] = O[q=n16][d=ct*16+quad*4+e]
  floatx4 o[8];
#pragma unroll
  for (int ct = 0; ct < 8; ct++) o[ct] = (floatx4){0.f, 0.f, 0.f, 0.f};
  float m_run = -1e30f, l_run = 0.f;        // per-lane scalars (row q = n16)

  _Float16* Pw = Psh + wave * 1152;         // this wave's 16 x 72 halves

  // prologue: tile 0 staged (latency exposed once)
  stage_load(jbase0);
  stage_write();
  __syncthreads();

  for (int it = 0; it < jcount; it++) {
    const int jbase = jbase0 + it * BN;
    // T14: issue next tile's K loads now; ds_write after post-compute barrier.
    if (it + 1 < jcount) stage_load(jbase + BN);

    // ---- S^T = K Q^T : s[t][e] = S[q=n16][key = t*16 + quad*4 + e]
    floatx4 s[4];
    __builtin_amdgcn_s_setprio(1);
#pragma unroll
    for (int t = 0; t < 4; t++) {
      s[t] = (floatx4){0.f, 0.f, 0.f, 0.f};
#pragma unroll
      for (int c = 0; c < 4; c++) {
        f16x8 kf = *(const f16x8*)&Ksh[(t * 16 + n16) * 136 + c * 32 + quad * 8];
        s[t] = __builtin_amdgcn_mfma_f32_16x16x32_f16(kf, qf[c], s[t], 0, 0, 0);
      }
    }
    __builtin_amdgcn_s_setprio(0);

    // ---- issue first-half V loads (ct 0..3): L2 latency hides under softmax
    f16x8 vgA[4][2];
#pragma unroll
    for (int ct = 0; ct < 4; ct++)
#pragma unroll
      for (int c = 0; c < 2; c++)
        vgA[ct][c] = *(const f16x8*)&Vg[(size_t)(ct * 16) * SEQ + jbase + c * 32];

    // ---- leaky_relu(0.2) + in-lane max over this lane's 16 keys
    float mx = -1e30f;
#pragma unroll
    for (int t = 0; t < 4; t++)
#pragma unroll
      for (int e = 0; e < 4; e++) {
        float v = s[t][e];
        v = v > 0.f ? v : 0.2f * v;
        s[t][e] = v;
        mx = fmaxf(mx, v);
      }
    mx = fmaxf(mx, __shfl_xor(mx, 16, 64));
    mx = fmaxf(mx, __shfl_xor(mx, 32, 64));

    // T13 defer-max: skip O/l rescale while tile max <= running max + 8.
    if (!__all(mx - m_run <= 8.f)) {
      float mnew = fmaxf(m_run, mx);
      float al   = __expf(m_run - mnew);
      m_run = mnew;
      l_run *= al;
#pragma unroll
      for (int ct = 0; ct < 8; ct++)
#pragma unroll
        for (int e = 0; e < 4; e++) o[ct][e] *= al;
    }

    // ---- P = exp(S - m), in-lane row-sum + 2 shfl
    float rs = 0.f;
#pragma unroll
    for (int t = 0; t < 4; t++)
#pragma unroll
      for (int e = 0; e < 4; e++) {
        float p = __expf(s[t][e] - m_run);
        s[t][e] = p;
        rs += p;
      }
    rs += __shfl_xor(rs, 16, 64);
    rs += __shfl_xor(rs, 32, 64);
    l_run += rs;

    // ---- P -> LDS (e-contiguous: 4x ds_write_b64), read back A-layout
#pragma unroll
    for (int t = 0; t < 4; t++) {
      f16x4 pw;
      pw[0] = (_Float16)s[t][0]; pw[1] = (_Float16)s[t][1];
      pw[2] = (_Float16)s[t][2]; pw[3] = (_Float16)s[t][3];
      *(f16x4*)&Pw[n16 * 72 + t * 16 + quad * 4] = pw;
    }
    asm volatile("s_waitcnt lgkmcnt(0)" ::: "memory");
    f16x8 pb[2];
#pragma unroll
    for (int c = 0; c < 2; c++)
      pb[c] = *(const f16x8*)&Pw[n16 * 72 + c * 32 + quad * 8];

    // ---- issue second-half V loads (ct 4..7): latency hides under PV half 1
    f16x8 vgB[4][2];
#pragma unroll
    for (int ct = 0; ct < 4; ct++)
#pragma unroll
      for (int c = 0; c < 2; c++)
        vgB[ct][c] = *(const f16x8*)&Vg[(size_t)((ct + 4) * 16) * SEQ + jbase + c * 32];

    // ---- O^T += V^T P^T
    __builtin_amdgcn_s_setprio(1);
#pragma unroll
    for (int ct = 0; ct < 4; ct++)
#pragma unroll
      for (int c = 0; c < 2; c++)
        o[ct] = __builtin_amdgcn_mfma_f32_16x16x32_f16(vgA[ct][c], pb[c], o[ct], 0, 0, 0);
#pragma unroll
    for (int ct = 0; ct < 4; ct++)
#pragma unroll
      for (int c = 0; c < 2; c++)
        o[ct + 4] = __builtin_amdgcn_mfma_f32_16x16x32_f16(vgB[ct][c], pb[c], o[ct + 4], 0, 0, 0);
    __builtin_amdgcn_s_setprio(0);

    __syncthreads();                       // all waves done reading Ksh
    if (it + 1 < jcount) {
      stage_write();                       // compiler inserts vmcnt waits
      __syncthreads();                     // tile it+1 ready
    }
  }

  // ---- write unnormalized partials: coalesced float4 stores
  float* Op = Opart + (size_t)sp * SEQ * DIM;
#pragma unroll
  for (int ct = 0; ct < 8; ct++)
    *(float4*)&Op[(size_t)(qbase + n16) * DIM + ct * 16 + quad * 4] =
        make_float4(o[ct][0], o[ct][1], o[ct][2], o[ct][3]);
  if (quad == 0) {
    mpart[sp * SEQ + qbase + n16] = m_run;
    lpart[sp * SEQ + qbase + n16] = l_run;
  }
}

// ---------------------------------------------------------------------------
// Kernel 3: log-sum-exp combine of NSPLIT partials -> out fp32 (float4/thread)
// ---------------------------------------------------------------------------
__global__ __launch_bounds__(256) void combine_kernel(
    const float* __restrict__ Opart, const float* __restrict__ mpart,
    const float* __restrict__ lpart, float* __restrict__ out) {
  int idx4 = blockIdx.x * 256 + threadIdx.x;   // 0 .. SEQ*DIM/4-1
  int row  = idx4 >> 5;                        // 32 float4 per row
  float M = -1e30f;
#pragma unroll
  for (int p = 0; p < NSPLIT; p++) M = fmaxf(M, mpart[p * SEQ + row]);
  float den = 0.f;
  float4 num = make_float4(0.f, 0.f, 0.f, 0.f);
#pragma unroll
  for (int p = 0; p < NSPLIT; p++) {
    float e = __expf(mpart[p * SEQ + row] - M);
    den += e * lpart[p * SEQ + row];
    float4 v = ((const float4*)Opart)[(size_t)p * (SEQ * DIM / 4) + idx4];
    num.x += e * v.x; num.y += e * v.y; num.z += e * v.z; num.w += e * v.w;
  }
  float inv = 1.f / den;
  ((float4*)out)[idx4] = make_float4(num.x * inv, num.y * inv,
                                     num.z * inv, num.w * inv);
}

// ---------------------------------------------------------------------------
extern "C" void kernel_launch(void* const* d_in, const int* in_sizes, int n_in,
                              void* d_out, int out_size, void* d_ws,
                              size_t ws_size, hipStream_t stream) {
  const float* h = (const float*)d_in[0];
  // d_in[1] = adj  (unused by the reference math)
  const float* W = (const float*)d_in[2];
  float* out = (float*)d_out;

  char* ws = (char*)d_ws;
  _Float16* Wh16  = (_Float16*)ws;                                 // 2 MiB
  _Float16* WhT16 = (_Float16*)(ws + (size_t)2 * 1024 * 1024);     // 2 MiB
  float* Opart = (float*)(ws + (size_t)4 * 1024 * 1024);           // 24 MiB
  float* mpart = (float*)(ws + (size_t)28 * 1024 * 1024);          // 192 KiB
  float* lpart = (float*)(ws + (size_t)28 * 1024 * 1024 + 256 * 1024);

  wh_kernel<<<SEQ / 64, 256, 0, stream>>>(h, W, Wh16, WhT16);
  dim3 grid(SEQ / BM, NSPLIT);
  flash_kernel<<<grid, 256, 0, stream>>>(Wh16, WhT16, Opart, mpart, lpart);
  combine_kernel<<<(SEQ * DIM / 4) / 256, 256, 0, stream>>>(Opart, mpart, lpart, out);
}

// Round 7
// 467.969 us; speedup vs baseline: 1.1491x; 1.1491x over previous
//
#include <hip/hip_runtime.h>

// GAT self-attention: Wh = h@W; out = softmax(leaky_relu(Wh@Wh^T)) @ Wh
// N=8192, IN_F=256, OUT_F=128. adj input unused by the math.
//
// Round 7: recovery. Flash reverted to the r3 version VERBATIM (best measured:
// 407.9us total; Vtsh LDS staging + T14 one-tile-ahead reg prefetch so all
// global latency is covered; 3 blocks/CU). r6's V-from-global is dropped:
// it replaced prefetched loads with on-demand loads and exposed L2 latency
// twice per tile (+130us). Kept: r4/r6 wh_kernel (LDS transpose -> coalesced
// f16x8 WhT16 stores; never cleanly measured, est -10us vs scalar scatter).

#define SEQ   8192
#define DIM   128
#define IN_F  256
#define BM    64
#define BN    64
#define NSPLIT 6
#define NKT   (SEQ / BN)      // 128 key tiles total

typedef __attribute__((ext_vector_type(8))) _Float16 f16x8;
typedef __attribute__((ext_vector_type(4))) _Float16 f16x4;
typedef __attribute__((ext_vector_type(4))) float   floatx4;

// ---------------------------------------------------------------------------
// Kernel 1: Wh = h @ W (fp32 accum) -> Wh16 row-major (coalesced) and WhT16
// via LDS transpose (coalesced f16x8 stores). 128 blocks x 64 rows.
// ---------------------------------------------------------------------------
__global__ __launch_bounds__(256) void wh_kernel(
    const float* __restrict__ h, const float* __restrict__ W,
    _Float16* __restrict__ Wh16, _Float16* __restrict__ WhT16) {
  __shared__ _Float16 T[64 * 132];            // pad 132 breaks pow-2 stride
  int tid = threadIdx.x;
  int cg  = tid & 31;                         // column group: 4 fp32 cols
  int rl  = tid >> 5;                         // 0..7
  int rowbase = blockIdx.x * 64;
  const float4* W4 = (const float4*)W;        // [256][32] of float4
#pragma unroll 2
  for (int sub = 0; sub < 8; sub++) {
    int row = rowbase + sub * 8 + rl;
    const float4* h4 = (const float4*)(h + (size_t)row * IN_F);
    float4 acc = make_float4(0.f, 0.f, 0.f, 0.f);
#pragma unroll 8
    for (int k4 = 0; k4 < IN_F / 4; k4++) {
      float4 hv = h4[k4];
      float4 w0 = W4[(k4 * 4 + 0) * 32 + cg];
      float4 w1 = W4[(k4 * 4 + 1) * 32 + cg];
      float4 w2 = W4[(k4 * 4 + 2) * 32 + cg];
      float4 w3 = W4[(k4 * 4 + 3) * 32 + cg];
      acc.x += hv.x * w0.x + hv.y * w1.x + hv.z * w2.x + hv.w * w3.x;
      acc.y += hv.x * w0.y + hv.y * w1.y + hv.z * w2.y + hv.w * w3.y;
      acc.z += hv.x * w0.z + hv.y * w1.z + hv.z * w2.z + hv.w * w3.z;
      acc.w += hv.x * w0.w + hv.y * w1.w + hv.z * w2.w + hv.w * w3.w;
    }
    f16x4 r;
    r[0] = (_Float16)acc.x; r[1] = (_Float16)acc.y;
    r[2] = (_Float16)acc.z; r[3] = (_Float16)acc.w;
    *(f16x4*)&Wh16[(size_t)row * DIM + cg * 4] = r;
    *(f16x4*)&T[(sub * 8 + rl) * 132 + cg * 4] = r;
  }
  __syncthreads();
  // WhT16[d][rowbase..+63]: 128 d x 8 row-chunks; 8 consecutive lanes write
  // 128B contiguous.
#pragma unroll
  for (int p = 0; p < 4; p++) {
    int chunk = p * 256 + tid;
    int d  = chunk >> 3;
    int rc = chunk & 7;
    f16x8 v;
#pragma unroll
    for (int i = 0; i < 8; i++) v[i] = T[(rc * 8 + i) * 132 + d];
    *(f16x8*)&WhT16[(size_t)d * SEQ + rowbase + rc * 8] = v;
  }
}

// ---------------------------------------------------------------------------
// Kernel 2: flash attention, swapped-QK^T form (r3 verbatim).
// grid = (128 qtiles, NSPLIT), block = 256 (4 waves); wave w owns Q rows
// [qtile*64 + w*16, +16).
// LDS: Ksh [64][136] + Vtsh [128][72] + Psh [4][16][72] = 22528 halves = 45KB.
// ---------------------------------------------------------------------------
__global__ __launch_bounds__(256, 3) void flash_kernel(
    const _Float16* __restrict__ Wh16, const _Float16* __restrict__ WhT16,
    float* __restrict__ Opart, float* __restrict__ mpart,
    float* __restrict__ lpart) {
  __shared__ _Float16 lds[22528];           // 45056 B
  _Float16* Ksh  = lds;                     // 64*136  = 8704 halves
  _Float16* Vtsh = lds + 8704;              // 128*72  = 9216
  _Float16* Psh  = lds + 8704 + 9216;       // 4*16*72 = 4608

  const int tid  = threadIdx.x;
  const int lane = tid & 63;
  const int wave = tid >> 6;
  const int n16  = lane & 15;
  const int quad = lane >> 4;

  const int qbase  = blockIdx.x * BM + wave * 16;
  const int sp     = blockIdx.y;
  const int tstart = (sp * NKT) / NSPLIT;
  const int tend   = ((sp + 1) * NKT) / NSPLIT;
  const int jbase0 = tstart * BN;
  const int jcount = tend - tstart;          // 21 or 22

  // Q fragments (B operand): qf[c] = Q[qbase+n16][c*32+quad*8+j]
  f16x8 qf[4];
#pragma unroll
  for (int c = 0; c < 4; c++)
    qf[c] = *(const f16x8*)&Wh16[(size_t)(qbase + n16) * DIM + c * 32 + quad * 8];

  // staging decomposition (identical to r2/r3)
  const int krow = tid >> 4;
  const int kcol = (tid & 15) * 8;
  const int vrow = tid >> 3;
  const int vcol = (tid & 7) * 8;
  f16x8 kreg[4], vreg[4];
  auto stage_load = [&](int jb) {
#pragma unroll
    for (int rep = 0; rep < 4; rep++)
      kreg[rep] = *(const f16x8*)&Wh16[(size_t)(jb + rep * 16 + krow) * DIM + kcol];
#pragma unroll
    for (int rep = 0; rep < 4; rep++)
      vreg[rep] = *(const f16x8*)&WhT16[(size_t)(rep * 32 + vrow) * SEQ + jb + vcol];
  };
  auto stage_write = [&]() {
#pragma unroll
    for (int rep = 0; rep < 4; rep++)
      *(f16x8*)&Ksh[(rep * 16 + krow) * 136 + kcol] = kreg[rep];
#pragma unroll
    for (int rep = 0; rep < 4; rep++)
      *(f16x8*)&Vtsh[(rep * 32 + vrow) * 72 + vcol] = vreg[rep];
  };

  // O^T accumulators: o[ct][e] = O[q=n16][d=ct*16+quad*4+e]
  floatx4 o[8];
#pragma unroll
  for (int ct = 0; ct < 8; ct++) o[ct] = (floatx4){0.f, 0.f, 0.f, 0.f};
  float m_run = -1e30f, l_run = 0.f;        // per-lane scalars (row q = n16)

  _Float16* Pw = Psh + wave * 1152;         // this wave's 16 x 72 halves

  // prologue: tile 0 staged (latency exposed once)
  stage_load(jbase0);
  stage_write();
  __syncthreads();

  for (int it = 0; it < jcount; it++) {
    // T14: issue next tile's global loads now; ds_write after the
    // post-compute barrier. Latency hides under this tile's compute.
    if (it + 1 < jcount) stage_load(jbase0 + (it + 1) * BN);

    // ---- S^T = K Q^T : s[t][e] = S[q=n16][key = t*16 + quad*4 + e]
    floatx4 s[4];
    __builtin_amdgcn_s_setprio(1);
#pragma unroll
    for (int t = 0; t < 4; t++) {
      s[t] = (floatx4){0.f, 0.f, 0.f, 0.f};
#pragma unroll
      for (int c = 0; c < 4; c++) {
        f16x8 kf = *(const f16x8*)&Ksh[(t * 16 + n16) * 136 + c * 32 + quad * 8];
        s[t] = __builtin_amdgcn_mfma_f32_16x16x32_f16(kf, qf[c], s[t], 0, 0, 0);
      }
    }
    __builtin_amdgcn_s_setprio(0);

    // ---- leaky_relu(0.2) + in-lane max over this lane's 16 keys
    float mx = -1e30f;
#pragma unroll
    for (int t = 0; t < 4; t++)
#pragma unroll
      for (int e = 0; e < 4; e++) {
        float v = s[t][e];
        v = v > 0.f ? v : 0.2f * v;
        s[t][e] = v;
        mx = fmaxf(mx, v);
      }
    mx = fmaxf(mx, __shfl_xor(mx, 16, 64));
    mx = fmaxf(mx, __shfl_xor(mx, 32, 64));

    // T13 defer-max: skip O/l rescale while tile max <= running max + 8.
    // P then bounded by e^8 ~ 2981, inside f16 range.
    if (!__all(mx - m_run <= 8.f)) {
      float mnew = fmaxf(m_run, mx);
      float al   = __expf(m_run - mnew);
      m_run = mnew;
      l_run *= al;
#pragma unroll
      for (int ct = 0; ct < 8; ct++)
#pragma unroll
        for (int e = 0; e < 4; e++) o[ct][e] *= al;
    }

    // ---- P = exp(S - m), in-lane row-sum + 2 shfl
    float rs = 0.f;
#pragma unroll
    for (int t = 0; t < 4; t++)
#pragma unroll
      for (int e = 0; e < 4; e++) {
        float p = __expf(s[t][e] - m_run);
        s[t][e] = p;
        rs += p;
      }
    rs += __shfl_xor(rs, 16, 64);
    rs += __shfl_xor(rs, 32, 64);
    l_run += rs;

    // ---- P -> LDS (e-contiguous: 4x ds_write_b64), read back A-layout
#pragma unroll
    for (int t = 0; t < 4; t++) {
      f16x4 pw;
      pw[0] = (_Float16)s[t][0]; pw[1] = (_Float16)s[t][1];
      pw[2] = (_Float16)s[t][2]; pw[3] = (_Float16)s[t][3];
      *(f16x4*)&Pw[n16 * 72 + t * 16 + quad * 4] = pw;
    }
    asm volatile("s_waitcnt lgkmcnt(0)" ::: "memory");
    f16x8 pb[2];
#pragma unroll
    for (int c = 0; c < 2; c++)
      pb[c] = *(const f16x8*)&Pw[n16 * 72 + c * 32 + quad * 8];

    // ---- O^T += V^T P^T
    __builtin_amdgcn_s_setprio(1);
#pragma unroll
    for (int ct = 0; ct < 8; ct++)
#pragma unroll
      for (int c = 0; c < 2; c++) {
        f16x8 vf = *(const f16x8*)&Vtsh[(ct * 16 + n16) * 72 + c * 32 + quad * 8];
        o[ct] = __builtin_amdgcn_mfma_f32_16x16x32_f16(vf, pb[c], o[ct], 0, 0, 0);
      }
    __builtin_amdgcn_s_setprio(0);

    __syncthreads();                       // all waves done reading tile it
    if (it + 1 < jcount) {
      stage_write();                       // compiler inserts vmcnt waits
      __syncthreads();                     // tile it+1 ready
    }
  }

  // ---- write unnormalized partials: coalesced float4 stores
  float* Op = Opart + (size_t)sp * SEQ * DIM;
#pragma unroll
  for (int ct = 0; ct < 8; ct++)
    *(float4*)&Op[(size_t)(qbase + n16) * DIM + ct * 16 + quad * 4] =
        make_float4(o[ct][0], o[ct][1], o[ct][2], o[ct][3]);
  if (quad == 0) {
    mpart[sp * SEQ + qbase + n16] = m_run;
    lpart[sp * SEQ + qbase + n16] = l_run;
  }
}

// ---------------------------------------------------------------------------
// Kernel 3: log-sum-exp combine of NSPLIT partials -> out fp32 (float4/thread)
// ---------------------------------------------------------------------------
__global__ __launch_bounds__(256) void combine_kernel(
    const float* __restrict__ Opart, const float* __restrict__ mpart,
    const float* __restrict__ lpart, float* __restrict__ out) {
  int idx4 = blockIdx.x * 256 + threadIdx.x;   // 0 .. SEQ*DIM/4-1
  int row  = idx4 >> 5;                        // 32 float4 per row
  float M = -1e30f;
#pragma unroll
  for (int p = 0; p < NSPLIT; p++) M = fmaxf(M, mpart[p * SEQ + row]);
  float den = 0.f;
  float4 num = make_float4(0.f, 0.f, 0.f, 0.f);
#pragma unroll
  for (int p = 0; p < NSPLIT; p++) {
    float e = __expf(mpart[p * SEQ + row] - M);
    den += e * lpart[p * SEQ + row];
    float4 v = ((const float4*)Opart)[(size_t)p * (SEQ * DIM / 4) + idx4];
    num.x += e * v.x; num.y += e * v.y; num.z += e * v.z; num.w += e * v.w;
  }
  float inv = 1.f / den;
  ((float4*)out)[idx4] = make_float4(num.x * inv, num.y * inv,
                                     num.z * inv, num.w * inv);
}

// ---------------------------------------------------------------------------
extern "C" void kernel_launch(void* const* d_in, const int* in_sizes, int n_in,
                              void* d_out, int out_size, void* d_ws,
                              size_t ws_size, hipStream_t stream) {
  const float* h = (const float*)d_in[0];
  // d_in[1] = adj  (unused by the reference math)
  const float* W = (const float*)d_in[2];
  float* out = (float*)d_out;

  char* ws = (char*)d_ws;
  _Float16* Wh16  = (_Float16*)ws;                                 // 2 MiB
  _Float16* WhT16 = (_Float16*)(ws + (size_t)2 * 1024 * 1024);     // 2 MiB
  float* Opart = (float*)(ws + (size_t)4 * 1024 * 1024);           // 24 MiB
  float* mpart = (float*)(ws + (size_t)28 * 1024 * 1024);          // 192 KiB
  float* lpart = (float*)(ws + (size_t)28 * 1024 * 1024 + 256 * 1024);

  wh_kernel<<<SEQ / 64, 256, 0, stream>>>(h, W, Wh16, WhT16);
  dim3 grid(SEQ / BM, NSPLIT);
  flash_kernel<<<grid, 256, 0, stream>>>(Wh16, WhT16, Opart, mpart, lpart);
  combine_kernel<<<(SEQ * DIM / 4) / 256, 256, 0, stream>>>(Opart, mpart, lpart, out);
}

// Round 8
// 404.461 us; speedup vs baseline: 1.3295x; 1.1570x over previous
//
#include <hip/hip_runtime.h>

// GAT self-attention: Wh = h@W; out = softmax(leaky_relu(Wh@Wh^T)) @ Wh
// N=8192, IN_F=256, OUT_F=128. adj input unused by the math.
//
// Round 8: r3 flash structure (best measured, 407.9us) + two isolated fixes:
//  - wh: KEEP the r3 grid (1024 blocks x 8 rows, proven compute) and fix ONLY
//    the WhT16 store path: 8x132 LDS bounce -> 128 f16x8 stores per block
//    (16B transactions, 4-8x fewer than the 2B scatter). r7's mistake was
//    shrinking the grid to 128 blocks (half the CUs idle), not the transpose.
//  - partials: flash writes O/l as f16 (|O/l| <= max|Wh| ~ 6, fits f16;
//    +~0.004 error vs 0.1175 threshold). Opart HBM traffic 48 -> 24 MiB.
// Flash kernel body itself is r3 VERBATIM except the epilogue normalization.

#define SEQ   8192
#define DIM   128
#define IN_F  256
#define BM    64
#define BN    64
#define NSPLIT 6
#define NKT   (SEQ / BN)      // 128 key tiles total

typedef __attribute__((ext_vector_type(8))) _Float16 f16x8;
typedef __attribute__((ext_vector_type(4))) _Float16 f16x4;
typedef __attribute__((ext_vector_type(4))) float   floatx4;

// ---------------------------------------------------------------------------
// Kernel 1: Wh = h @ W (fp32 accum) -> Wh16 row-major and WhT16.
// 1024 blocks x 8 rows (r3 geometry). WhT16 via 8x132 LDS bounce:
// per block, 128 f16x8 coalesced-gather stores instead of 1M-wide 2B scatter.
// ---------------------------------------------------------------------------
__global__ __launch_bounds__(256) void wh_kernel(
    const float* __restrict__ h, const float* __restrict__ W,
    _Float16* __restrict__ Wh16, _Float16* __restrict__ WhT16) {
  __shared__ _Float16 T[8 * 132];             // pad 132: transpose reads hit all banks
  int tid = threadIdx.x;
  int cg  = tid & 31;         // column group: 4 fp32 cols
  int rl  = tid >> 5;         // 0..7
  int row = blockIdx.x * 8 + rl;
  const float4* W4 = (const float4*)W;          // [256][32] of float4
  const float4* h4 = (const float4*)(h + (size_t)row * IN_F);
  float4 acc = make_float4(0.f, 0.f, 0.f, 0.f);
#pragma unroll 8
  for (int k4 = 0; k4 < IN_F / 4; k4++) {
    float4 hv = h4[k4];
    float4 w0 = W4[(k4 * 4 + 0) * 32 + cg];
    float4 w1 = W4[(k4 * 4 + 1) * 32 + cg];
    float4 w2 = W4[(k4 * 4 + 2) * 32 + cg];
    float4 w3 = W4[(k4 * 4 + 3) * 32 + cg];
    acc.x += hv.x * w0.x + hv.y * w1.x + hv.z * w2.x + hv.w * w3.x;
    acc.y += hv.x * w0.y + hv.y * w1.y + hv.z * w2.y + hv.w * w3.y;
    acc.z += hv.x * w0.z + hv.y * w1.z + hv.z * w2.z + hv.w * w3.z;
    acc.w += hv.x * w0.w + hv.y * w1.w + hv.z * w2.w + hv.w * w3.w;
  }
  f16x4 r;
  r[0] = (_Float16)acc.x; r[1] = (_Float16)acc.y;
  r[2] = (_Float16)acc.z; r[3] = (_Float16)acc.w;
  *(f16x4*)&Wh16[(size_t)row * DIM + cg * 4] = r;
  *(f16x4*)&T[rl * 132 + cg * 4] = r;
  __syncthreads();
  if (tid < 128) {
    int d = tid;                              // one d-column per thread
    f16x8 v;
#pragma unroll
    for (int i = 0; i < 8; i++) v[i] = T[i * 132 + d];
    *(f16x8*)&WhT16[(size_t)d * SEQ + blockIdx.x * 8] = v;
  }
}

// ---------------------------------------------------------------------------
// Kernel 2: flash attention, swapped-QK^T form (r3 verbatim body).
// grid = (128 qtiles, NSPLIT), block = 256 (4 waves); wave w owns Q rows
// [qtile*64 + w*16, +16).
// LDS: Ksh [64][136] + Vtsh [128][72] + Psh [4][16][72] = 22528 halves = 45KB.
// Epilogue: writes O/l as f16 (normalized partials), m/l fp32.
// ---------------------------------------------------------------------------
__global__ __launch_bounds__(256, 3) void flash_kernel(
    const _Float16* __restrict__ Wh16, const _Float16* __restrict__ WhT16,
    _Float16* __restrict__ Opart16, float* __restrict__ mpart,
    float* __restrict__ lpart) {
  __shared__ _Float16 lds[22528];           // 45056 B
  _Float16* Ksh  = lds;                     // 64*136  = 8704 halves
  _Float16* Vtsh = lds + 8704;              // 128*72  = 9216
  _Float16* Psh  = lds + 8704 + 9216;       // 4*16*72 = 4608

  const int tid  = threadIdx.x;
  const int lane = tid & 63;
  const int wave = tid >> 6;
  const int n16  = lane & 15;
  const int quad = lane >> 4;

  const int qbase  = blockIdx.x * BM + wave * 16;
  const int sp     = blockIdx.y;
  const int tstart = (sp * NKT) / NSPLIT;
  const int tend   = ((sp + 1) * NKT) / NSPLIT;
  const int jbase0 = tstart * BN;
  const int jcount = tend - tstart;          // 21 or 22

  // Q fragments (B operand): qf[c] = Q[qbase+n16][c*32+quad*8+j]
  f16x8 qf[4];
#pragma unroll
  for (int c = 0; c < 4; c++)
    qf[c] = *(const f16x8*)&Wh16[(size_t)(qbase + n16) * DIM + c * 32 + quad * 8];

  // staging decomposition (identical to r2/r3)
  const int krow = tid >> 4;
  const int kcol = (tid & 15) * 8;
  const int vrow = tid >> 3;
  const int vcol = (tid & 7) * 8;
  f16x8 kreg[4], vreg[4];
  auto stage_load = [&](int jb) {
#pragma unroll
    for (int rep = 0; rep < 4; rep++)
      kreg[rep] = *(const f16x8*)&Wh16[(size_t)(jb + rep * 16 + krow) * DIM + kcol];
#pragma unroll
    for (int rep = 0; rep < 4; rep++)
      vreg[rep] = *(const f16x8*)&WhT16[(size_t)(rep * 32 + vrow) * SEQ + jb + vcol];
  };
  auto stage_write = [&]() {
#pragma unroll
    for (int rep = 0; rep < 4; rep++)
      *(f16x8*)&Ksh[(rep * 16 + krow) * 136 + kcol] = kreg[rep];
#pragma unroll
    for (int rep = 0; rep < 4; rep++)
      *(f16x8*)&Vtsh[(rep * 32 + vrow) * 72 + vcol] = vreg[rep];
  };

  // O^T accumulators: o[ct][e] = O[q=n16][d=ct*16+quad*4+e]
  floatx4 o[8];
#pragma unroll
  for (int ct = 0; ct < 8; ct++) o[ct] = (floatx4){0.f, 0.f, 0.f, 0.f};
  float m_run = -1e30f, l_run = 0.f;        // per-lane scalars (row q = n16)

  _Float16* Pw = Psh + wave * 1152;         // this wave's 16 x 72 halves

  // prologue: tile 0 staged (latency exposed once)
  stage_load(jbase0);
  stage_write();
  __syncthreads();

  for (int it = 0; it < jcount; it++) {
    // T14: issue next tile's global loads now; ds_write after the
    // post-compute barrier. Latency hides under this tile's compute.
    if (it + 1 < jcount) stage_load(jbase0 + (it + 1) * BN);

    // ---- S^T = K Q^T : s[t][e] = S[q=n16][key = t*16 + quad*4 + e]
    floatx4 s[4];
    __builtin_amdgcn_s_setprio(1);
#pragma unroll
    for (int t = 0; t < 4; t++) {
      s[t] = (floatx4){0.f, 0.f, 0.f, 0.f};
#pragma unroll
      for (int c = 0; c < 4; c++) {
        f16x8 kf = *(const f16x8*)&Ksh[(t * 16 + n16) * 136 + c * 32 + quad * 8];
        s[t] = __builtin_amdgcn_mfma_f32_16x16x32_f16(kf, qf[c], s[t], 0, 0, 0);
      }
    }
    __builtin_amdgcn_s_setprio(0);

    // ---- leaky_relu(0.2) + in-lane max over this lane's 16 keys
    float mx = -1e30f;
#pragma unroll
    for (int t = 0; t < 4; t++)
#pragma unroll
      for (int e = 0; e < 4; e++) {
        float v = s[t][e];
        v = v > 0.f ? v : 0.2f * v;
        s[t][e] = v;
        mx = fmaxf(mx, v);
      }
    mx = fmaxf(mx, __shfl_xor(mx, 16, 64));
    mx = fmaxf(mx, __shfl_xor(mx, 32, 64));

    // T13 defer-max: skip O/l rescale while tile max <= running max + 8.
    // P then bounded by e^8 ~ 2981, inside f16 range.
    if (!__all(mx - m_run <= 8.f)) {
      float mnew = fmaxf(m_run, mx);
      float al   = __expf(m_run - mnew);
      m_run = mnew;
      l_run *= al;
#pragma unroll
      for (int ct = 0; ct < 8; ct++)
#pragma unroll
        for (int e = 0; e < 4; e++) o[ct][e] *= al;
    }

    // ---- P = exp(S - m), in-lane row-sum + 2 shfl
    float rs = 0.f;
#pragma unroll
    for (int t = 0; t < 4; t++)
#pragma unroll
      for (int e = 0; e < 4; e++) {
        float p = __expf(s[t][e] - m_run);
        s[t][e] = p;
        rs += p;
      }
    rs += __shfl_xor(rs, 16, 64);
    rs += __shfl_xor(rs, 32, 64);
    l_run += rs;

    // ---- P -> LDS (e-contiguous: 4x ds_write_b64), read back A-layout
#pragma unroll
    for (int t = 0; t < 4; t++) {
      f16x4 pw;
      pw[0] = (_Float16)s[t][0]; pw[1] = (_Float16)s[t][1];
      pw[2] = (_Float16)s[t][2]; pw[3] = (_Float16)s[t][3];
      *(f16x4*)&Pw[n16 * 72 + t * 16 + quad * 4] = pw;
    }
    asm volatile("s_waitcnt lgkmcnt(0)" ::: "memory");
    f16x8 pb[2];
#pragma unroll
    for (int c = 0; c < 2; c++)
      pb[c] = *(const f16x8*)&Pw[n16 * 72 + c * 32 + quad * 8];

    // ---- O^T += V^T P^T
    __builtin_amdgcn_s_setprio(1);
#pragma unroll
    for (int ct = 0; ct < 8; ct++)
#pragma unroll
      for (int c = 0; c < 2; c++) {
        f16x8 vf = *(const f16x8*)&Vtsh[(ct * 16 + n16) * 72 + c * 32 + quad * 8];
        o[ct] = __builtin_amdgcn_mfma_f32_16x16x32_f16(vf, pb[c], o[ct], 0, 0, 0);
      }
    __builtin_amdgcn_s_setprio(0);

    __syncthreads();                       // all waves done reading tile it
    if (it + 1 < jcount) {
      stage_write();                       // compiler inserts vmcnt waits
      __syncthreads();                     // tile it+1 ready
    }
  }

  // ---- write NORMALIZED partials O/l as f16 (bounded ~|Wh|max ~ 6)
  float linv = 1.f / l_run;
  _Float16* Op = Opart16 + (size_t)sp * SEQ * DIM;
#pragma unroll
  for (int ct = 0; ct < 8; ct++) {
    f16x4 ov;
    ov[0] = (_Float16)(o[ct][0] * linv); ov[1] = (_Float16)(o[ct][1] * linv);
    ov[2] = (_Float16)(o[ct][2] * linv); ov[3] = (_Float16)(o[ct][3] * linv);
    *(f16x4*)&Op[(size_t)(qbase + n16) * DIM + ct * 16 + quad * 4] = ov;
  }
  if (quad == 0) {
    mpart[sp * SEQ + qbase + n16] = m_run;
    lpart[sp * SEQ + qbase + n16] = l_run;
  }
}

// ---------------------------------------------------------------------------
// Kernel 3: combine normalized partials: out = sum_p w_p*(O_p/l_p) / sum_p w_p
// with w_p = exp(m_p - M) * l_p. f16x4 loads, float4 store.
// ---------------------------------------------------------------------------
__global__ __launch_bounds__(256) void combine_kernel(
    const _Float16* __restrict__ Opart16, const float* __restrict__ mpart,
    const float* __restrict__ lpart, float* __restrict__ out) {
  int idx4 = blockIdx.x * 256 + threadIdx.x;   // 0 .. SEQ*DIM/4-1
  int row  = idx4 >> 5;                        // 32 four-element chunks per row
  float M = -1e30f;
#pragma unroll
  for (int p = 0; p < NSPLIT; p++) M = fmaxf(M, mpart[p * SEQ + row]);
  float den = 0.f;
  float4 num = make_float4(0.f, 0.f, 0.f, 0.f);
#pragma unroll
  for (int p = 0; p < NSPLIT; p++) {
    float w = __expf(mpart[p * SEQ + row] - M) * lpart[p * SEQ + row];
    f16x4 v = *(const f16x4*)&Opart16[(size_t)p * SEQ * DIM + (size_t)idx4 * 4];
    num.x += w * (float)v[0]; num.y += w * (float)v[1];
    num.z += w * (float)v[2]; num.w += w * (float)v[3];
    den += w;
  }
  float inv = 1.f / den;
  ((float4*)out)[idx4] = make_float4(num.x * inv, num.y * inv,
                                     num.z * inv, num.w * inv);
}

// ---------------------------------------------------------------------------
extern "C" void kernel_launch(void* const* d_in, const int* in_sizes, int n_in,
                              void* d_out, int out_size, void* d_ws,
                              size_t ws_size, hipStream_t stream) {
  const float* h = (const float*)d_in[0];
  // d_in[1] = adj  (unused by the reference math)
  const float* W = (const float*)d_in[2];
  float* out = (float*)d_out;

  char* ws = (char*)d_ws;
  _Float16* Wh16    = (_Float16*)ws;                               // 2 MiB
  _Float16* WhT16   = (_Float16*)(ws + (size_t)2 * 1024 * 1024);   // 2 MiB
  _Float16* Opart16 = (_Float16*)(ws + (size_t)4 * 1024 * 1024);   // 12 MiB
  float* mpart = (float*)(ws + (size_t)16 * 1024 * 1024);          // 192 KiB
  float* lpart = (float*)(ws + (size_t)16 * 1024 * 1024 + 256 * 1024);

  wh_kernel<<<SEQ / 8, 256, 0, stream>>>(h, W, Wh16, WhT16);
  dim3 grid(SEQ / BM, NSPLIT);
  flash_kernel<<<grid, 256, 0, stream>>>(Wh16, WhT16, Opart16, mpart, lpart);
  combine_kernel<<<(SEQ * DIM / 4) / 256, 256, 0, stream>>>(Opart16, mpart, lpart, out);
}

// Round 9
// 372.535 us; speedup vs baseline: 1.4434x; 1.0857x over previous
//
#include <hip/hip_runtime.h>

// GAT self-attention: Wh = h@W; out = softmax(leaky_relu(Wh@Wh^T)) @ Wh
// N=8192, IN_F=256, OUT_F=128. adj input unused by the math.
//
// Round 9: wh via MFMA (Guideline 10 — it's matmul-shaped, K=256):
//  - wprep: W (fp32 [256][128]) -> Wt16 = W^T f16 [128][256] (64 KB, L2-hot)
//  - wh: 512 blocks x 16 rows, 4 waves x 2 d-tiles. Both MFMA orientations
//    (o = mfma(wf,hf), o2 = mfma(hf,wf)) give coalesced f16x4 stores for
//    Wh16 AND WhT16 — same verified fragment algebra as flash's swapped QK^T.
//    Replaces 1024 fp32 VALU FMAs + 256 W-float4 loads per thread.
// Flash + combine are r8-verbatim (404.5us best) except leaky_relu as
// fmaxf(v, 0.2v) (branch-free identity: x>0 -> x, x<0 -> 0.2x).

#define SEQ   8192
#define DIM   128
#define IN_F  256
#define BM    64
#define BN    64
#define NSPLIT 6
#define NKT   (SEQ / BN)      // 128 key tiles total

typedef __attribute__((ext_vector_type(8))) _Float16 f16x8;
typedef __attribute__((ext_vector_type(4))) _Float16 f16x4;
typedef __attribute__((ext_vector_type(4))) float   floatx4;

// ---------------------------------------------------------------------------
// Kernel 0: Wt16[d][k] = (f16) W[k][d].  4096 units of (d, 8-k chunk).
// ---------------------------------------------------------------------------
__global__ __launch_bounds__(256) void wprep_kernel(
    const float* __restrict__ W, _Float16* __restrict__ Wt16) {
  int u = blockIdx.x * 256 + threadIdx.x;     // 0..4095
  int d  = u >> 5;
  int k8 = (u & 31) * 8;
  f16x8 v;
#pragma unroll
  for (int i = 0; i < 8; i++) v[i] = (_Float16)W[(size_t)(k8 + i) * DIM + d];
  *(f16x8*)&Wt16[(size_t)d * IN_F + k8] = v;
}

// ---------------------------------------------------------------------------
// Kernel 1: Wh = h @ W via mfma_f32_16x16x32_f16, dual orientation.
// 512 blocks x 16 q-rows; wave w owns d-tiles {2w, 2w+1}.
//   o  = mfma(wf, hf): lane(n16,quad) e -> Wh[qbase+n16][t*16+quad*4+e]
//   o2 = mfma(hf, wf): lane(n16,quad) e -> Wh[qbase+quad*4+e][t*16+n16]
// ---------------------------------------------------------------------------
__global__ __launch_bounds__(256) void wh_kernel(
    const float* __restrict__ h, const _Float16* __restrict__ Wt16,
    _Float16* __restrict__ Wh16, _Float16* __restrict__ WhT16) {
  const int tid  = threadIdx.x;
  const int lane = tid & 63;
  const int wave = tid >> 6;
  const int n16  = lane & 15;
  const int quad = lane >> 4;
  const int qbase = blockIdx.x * 16;

  // hf[c] = (f16) h[qbase+n16][c*32 + quad*8 .. +7]
  f16x8 hf[8];
  const float* hrow = h + (size_t)(qbase + n16) * IN_F + quad * 8;
#pragma unroll
  for (int c = 0; c < 8; c++) {
    float4 a = *(const float4*)&hrow[c * 32];
    float4 b = *(const float4*)&hrow[c * 32 + 4];
    f16x8 v;
    v[0] = (_Float16)a.x; v[1] = (_Float16)a.y;
    v[2] = (_Float16)a.z; v[3] = (_Float16)a.w;
    v[4] = (_Float16)b.x; v[5] = (_Float16)b.y;
    v[6] = (_Float16)b.z; v[7] = (_Float16)b.w;
    hf[c] = v;
  }

#pragma unroll
  for (int ti = 0; ti < 2; ti++) {
    const int t = wave * 2 + ti;
    floatx4 o  = (floatx4){0.f, 0.f, 0.f, 0.f};
    floatx4 o2 = (floatx4){0.f, 0.f, 0.f, 0.f};
#pragma unroll
    for (int c = 0; c < 8; c++) {
      f16x8 wf = *(const f16x8*)&Wt16[(size_t)(t * 16 + n16) * IN_F
                                      + c * 32 + quad * 8];
      o  = __builtin_amdgcn_mfma_f32_16x16x32_f16(wf, hf[c], o,  0, 0, 0);
      o2 = __builtin_amdgcn_mfma_f32_16x16x32_f16(hf[c], wf, o2, 0, 0, 0);
    }
    f16x4 r;
    r[0] = (_Float16)o[0]; r[1] = (_Float16)o[1];
    r[2] = (_Float16)o[2]; r[3] = (_Float16)o[3];
    *(f16x4*)&Wh16[(size_t)(qbase + n16) * DIM + t * 16 + quad * 4] = r;
    f16x4 rt;
    rt[0] = (_Float16)o2[0]; rt[1] = (_Float16)o2[1];
    rt[2] = (_Float16)o2[2]; rt[3] = (_Float16)o2[3];
    *(f16x4*)&WhT16[(size_t)(t * 16 + n16) * SEQ + qbase + quad * 4] = rt;
  }
}

// ---------------------------------------------------------------------------
// Kernel 2: flash attention, swapped-QK^T form (r3/r8 verbatim body).
// grid = (128 qtiles, NSPLIT), block = 256 (4 waves); wave w owns Q rows
// [qtile*64 + w*16, +16).
// LDS: Ksh [64][136] + Vtsh [128][72] + Psh [4][16][72] = 22528 halves = 45KB.
// Epilogue: writes O/l as f16 (normalized partials), m/l fp32.
// ---------------------------------------------------------------------------
__global__ __launch_bounds__(256, 3) void flash_kernel(
    const _Float16* __restrict__ Wh16, const _Float16* __restrict__ WhT16,
    _Float16* __restrict__ Opart16, float* __restrict__ mpart,
    float* __restrict__ lpart) {
  __shared__ _Float16 lds[22528];           // 45056 B
  _Float16* Ksh  = lds;                     // 64*136  = 8704 halves
  _Float16* Vtsh = lds + 8704;              // 128*72  = 9216
  _Float16* Psh  = lds + 8704 + 9216;       // 4*16*72 = 4608

  const int tid  = threadIdx.x;
  const int lane = tid & 63;
  const int wave = tid >> 6;
  const int n16  = lane & 15;
  const int quad = lane >> 4;

  const int qbase  = blockIdx.x * BM + wave * 16;
  const int sp     = blockIdx.y;
  const int tstart = (sp * NKT) / NSPLIT;
  const int tend   = ((sp + 1) * NKT) / NSPLIT;
  const int jbase0 = tstart * BN;
  const int jcount = tend - tstart;          // 21 or 22

  // Q fragments (B operand): qf[c] = Q[qbase+n16][c*32+quad*8+j]
  f16x8 qf[4];
#pragma unroll
  for (int c = 0; c < 4; c++)
    qf[c] = *(const f16x8*)&Wh16[(size_t)(qbase + n16) * DIM + c * 32 + quad * 8];

  // staging decomposition (identical to r2/r3)
  const int krow = tid >> 4;
  const int kcol = (tid & 15) * 8;
  const int vrow = tid >> 3;
  const int vcol = (tid & 7) * 8;
  f16x8 kreg[4], vreg[4];
  auto stage_load = [&](int jb) {
#pragma unroll
    for (int rep = 0; rep < 4; rep++)
      kreg[rep] = *(const f16x8*)&Wh16[(size_t)(jb + rep * 16 + krow) * DIM + kcol];
#pragma unroll
    for (int rep = 0; rep < 4; rep++)
      vreg[rep] = *(const f16x8*)&WhT16[(size_t)(rep * 32 + vrow) * SEQ + jb + vcol];
  };
  auto stage_write = [&]() {
#pragma unroll
    for (int rep = 0; rep < 4; rep++)
      *(f16x8*)&Ksh[(rep * 16 + krow) * 136 + kcol] = kreg[rep];
#pragma unroll
    for (int rep = 0; rep < 4; rep++)
      *(f16x8*)&Vtsh[(rep * 32 + vrow) * 72 + vcol] = vreg[rep];
  };

  // O^T accumulators: o[ct][e] = O[q=n16][d=ct*16+quad*4+e]
  floatx4 o[8];
#pragma unroll
  for (int ct = 0; ct < 8; ct++) o[ct] = (floatx4){0.f, 0.f, 0.f, 0.f};
  float m_run = -1e30f, l_run = 0.f;        // per-lane scalars (row q = n16)

  _Float16* Pw = Psh + wave * 1152;         // this wave's 16 x 72 halves

  // prologue: tile 0 staged (latency exposed once)
  stage_load(jbase0);
  stage_write();
  __syncthreads();

  for (int it = 0; it < jcount; it++) {
    // T14: issue next tile's global loads now; ds_write after the
    // post-compute barrier. Latency hides under this tile's compute.
    if (it + 1 < jcount) stage_load(jbase0 + (it + 1) * BN);

    // ---- S^T = K Q^T : s[t][e] = S[q=n16][key = t*16 + quad*4 + e]
    floatx4 s[4];
    __builtin_amdgcn_s_setprio(1);
#pragma unroll
    for (int t = 0; t < 4; t++) {
      s[t] = (floatx4){0.f, 0.f, 0.f, 0.f};
#pragma unroll
      for (int c = 0; c < 4; c++) {
        f16x8 kf = *(const f16x8*)&Ksh[(t * 16 + n16) * 136 + c * 32 + quad * 8];
        s[t] = __builtin_amdgcn_mfma_f32_16x16x32_f16(kf, qf[c], s[t], 0, 0, 0);
      }
    }
    __builtin_amdgcn_s_setprio(0);

    // ---- leaky_relu(0.2) = fmax(x, 0.2x) + in-lane max over 16 keys
    float mx = -1e30f;
#pragma unroll
    for (int t = 0; t < 4; t++)
#pragma unroll
      for (int e = 0; e < 4; e++) {
        float v = fmaxf(s[t][e], 0.2f * s[t][e]);
        s[t][e] = v;
        mx = fmaxf(mx, v);
      }
    mx = fmaxf(mx, __shfl_xor(mx, 16, 64));
    mx = fmaxf(mx, __shfl_xor(mx, 32, 64));

    // T13 defer-max: skip O/l rescale while tile max <= running max + 8.
    // P then bounded by e^8 ~ 2981, inside f16 range.
    if (!__all(mx - m_run <= 8.f)) {
      float mnew = fmaxf(m_run, mx);
      float al   = __expf(m_run - mnew);
      m_run = mnew;
      l_run *= al;
#pragma unroll
      for (int ct = 0; ct < 8; ct++)
#pragma unroll
        for (int e = 0; e < 4; e++) o[ct][e] *= al;
    }

    // ---- P = exp(S - m), in-lane row-sum + 2 shfl
    float rs = 0.f;
#pragma unroll
    for (int t = 0; t < 4; t++)
#pragma unroll
      for (int e = 0; e < 4; e++) {
        float p = __expf(s[t][e] - m_run);
        s[t][e] = p;
        rs += p;
      }
    rs += __shfl_xor(rs, 16, 64);
    rs += __shfl_xor(rs, 32, 64);
    l_run += rs;

    // ---- P -> LDS (e-contiguous: 4x ds_write_b64), read back A-layout
#pragma unroll
    for (int t = 0; t < 4; t++) {
      f16x4 pw;
      pw[0] = (_Float16)s[t][0]; pw[1] = (_Float16)s[t][1];
      pw[2] = (_Float16)s[t][2]; pw[3] = (_Float16)s[t][3];
      *(f16x4*)&Pw[n16 * 72 + t * 16 + quad * 4] = pw;
    }
    asm volatile("s_waitcnt lgkmcnt(0)" ::: "memory");
    f16x8 pb[2];
#pragma unroll
    for (int c = 0; c < 2; c++)
      pb[c] = *(const f16x8*)&Pw[n16 * 72 + c * 32 + quad * 8];

    // ---- O^T += V^T P^T
    __builtin_amdgcn_s_setprio(1);
#pragma unroll
    for (int ct = 0; ct < 8; ct++)
#pragma unroll
      for (int c = 0; c < 2; c++) {
        f16x8 vf = *(const f16x8*)&Vtsh[(ct * 16 + n16) * 72 + c * 32 + quad * 8];
        o[ct] = __builtin_amdgcn_mfma_f32_16x16x32_f16(vf, pb[c], o[ct], 0, 0, 0);
      }
    __builtin_amdgcn_s_setprio(0);

    __syncthreads();                       // all waves done reading tile it
    if (it + 1 < jcount) {
      stage_write();                       // compiler inserts vmcnt waits
      __syncthreads();                     // tile it+1 ready
    }
  }

  // ---- write NORMALIZED partials O/l as f16 (bounded ~|Wh|max ~ 6)
  float linv = 1.f / l_run;
  _Float16* Op = Opart16 + (size_t)sp * SEQ * DIM;
#pragma unroll
  for (int ct = 0; ct < 8; ct++) {
    f16x4 ov;
    ov[0] = (_Float16)(o[ct][0] * linv); ov[1] = (_Float16)(o[ct][1] * linv);
    ov[2] = (_Float16)(o[ct][2] * linv); ov[3] = (_Float16)(o[ct][3] * linv);
    *(f16x4*)&Op[(size_t)(qbase + n16) * DIM + ct * 16 + quad * 4] = ov;
  }
  if (quad == 0) {
    mpart[sp * SEQ + qbase + n16] = m_run;
    lpart[sp * SEQ + qbase + n16] = l_run;
  }
}

// ---------------------------------------------------------------------------
// Kernel 3: combine normalized partials: out = sum_p w_p*(O_p/l_p) / sum_p w_p
// with w_p = exp(m_p - M) * l_p. f16x4 loads, float4 store.
// ---------------------------------------------------------------------------
__global__ __launch_bounds__(256) void combine_kernel(
    const _Float16* __restrict__ Opart16, const float* __restrict__ mpart,
    const float* __restrict__ lpart, float* __restrict__ out) {
  int idx4 = blockIdx.x * 256 + threadIdx.x;   // 0 .. SEQ*DIM/4-1
  int row  = idx4 >> 5;                        // 32 four-element chunks per row
  float M = -1e30f;
#pragma unroll
  for (int p = 0; p < NSPLIT; p++) M = fmaxf(M, mpart[p * SEQ + row]);
  float den = 0.f;
  float4 num = make_float4(0.f, 0.f, 0.f, 0.f);
#pragma unroll
  for (int p = 0; p < NSPLIT; p++) {
    float w = __expf(mpart[p * SEQ + row] - M) * lpart[p * SEQ + row];
    f16x4 v = *(const f16x4*)&Opart16[(size_t)p * SEQ * DIM + (size_t)idx4 * 4];
    num.x += w * (float)v[0]; num.y += w * (float)v[1];
    num.z += w * (float)v[2]; num.w += w * (float)v[3];
    den += w;
  }
  float inv = 1.f / den;
  ((float4*)out)[idx4] = make_float4(num.x * inv, num.y * inv,
                                     num.z * inv, num.w * inv);
}

// ---------------------------------------------------------------------------
extern "C" void kernel_launch(void* const* d_in, const int* in_sizes, int n_in,
                              void* d_out, int out_size, void* d_ws,
                              size_t ws_size, hipStream_t stream) {
  const float* h = (const float*)d_in[0];
  // d_in[1] = adj  (unused by the reference math)
  const float* W = (const float*)d_in[2];
  float* out = (float*)d_out;

  char* ws = (char*)d_ws;
  _Float16* Wh16    = (_Float16*)ws;                               // 2 MiB
  _Float16* WhT16   = (_Float16*)(ws + (size_t)2 * 1024 * 1024);   // 2 MiB
  _Float16* Opart16 = (_Float16*)(ws + (size_t)4 * 1024 * 1024);   // 12 MiB
  float* mpart = (float*)(ws + (size_t)16 * 1024 * 1024);          // 192 KiB
  float* lpart = (float*)(ws + (size_t)16 * 1024 * 1024 + 256 * 1024);
  _Float16* Wt16 = (_Float16*)(ws + (size_t)17 * 1024 * 1024);     // 64 KiB

  wprep_kernel<<<16, 256, 0, stream>>>(W, Wt16);
  wh_kernel<<<SEQ / 16, 256, 0, stream>>>(h, Wt16, Wh16, WhT16);
  dim3 grid(SEQ / BM, NSPLIT);
  flash_kernel<<<grid, 256, 0, stream>>>(Wh16, WhT16, Opart16, mpart, lpart);
  combine_kernel<<<(SEQ * DIM / 4) / 256, 256, 0, stream>>>(Opart16, mpart, lpart, out);
}